// Round 6
// baseline (160.529 us; speedup 1.0000x reference)
//
#include <hip/hip_runtime.h>
#include <hip/hip_bf16.h>

// Problem constants (B,G,D,H,K,V) = (4, 2048, 128, 8, 16, 16)
#define GG 2048
#define DD 128
#define HH 8
#define BH 32

typedef _Float16 h2 __attribute__((ext_vector_type(2)));
typedef _Float16 h4 __attribute__((ext_vector_type(4)));
typedef _Float16 h8 __attribute__((ext_vector_type(8)));
typedef __attribute__((ext_vector_type(4))) float f32x4;
typedef unsigned short u16;
typedef unsigned int   u32;
typedef unsigned char  u8;
typedef unsigned long long u64;

// 0.25 (=1/sqrt(16)) * log2(e): folded into W_Q so softmax uses raw exp2.
#define QSCALE 0.36067376022224085f

// ws layout (f16), ~8.6 MB total
#define OFF_Q 0u            // f16 [BH][G][16] (scaled)   2 MB
#define OFF_K (2u << 20)    // f16 [BH][G][16]            2 MB
#define OFF_V (4u << 20)    // f16 [BH][16][G] (V^T)      2 MB
#define OFF_M (6u << 20)    // u8  [G][G/8] mask bytes  512 KB
#define OFF_H 6815744u      // f16 h [B][G][128]          2 MB
#define OFF_W 8912896u      // f16 Wc [H][48][128]       96 KB

#if __has_builtin(__builtin_amdgcn_exp2f)
#define EXP2F(x) __builtin_amdgcn_exp2f(x)
#else
#define EXP2F(x) exp2f(x)
#endif

// Legacy K=16 f16 MFMA — LLVM name has NO underscore before f16 (gfx908-era
// naming). Direct call: amdgcn builtins parse on both HIP compile passes
// (evidence: rounds 1-4), __has_builtin is false on the host pass.
#define MFMA16(a, b, c) __builtin_amdgcn_mfma_f32_16x16x16f16(a, b, c, 0, 0, 0)

// ---------------------------------------------------------------------------
// Kernel 1 (fused streaming prep):
//   blocks [0,512):      h fp32 -> f16            (8 elems/thread)
//   blocks [512,704):    W pack -> Wc[h][48][128] f16, QSCALE in Q cols
//   blocks [704,2752):   mask int32 -> byte map   (8 elems/thread, 1 u8 store)
// ---------------------------------------------------------------------------
__global__ __launch_bounds__(256) void prep_kernel(
    const float* __restrict__ h, const int* __restrict__ mask,
    const float* __restrict__ WQ, const float* __restrict__ WK,
    const float* __restrict__ WV,
    _Float16* __restrict__ hF, _Float16* __restrict__ Wc, u8* __restrict__ mb)
{
  const int blk = blockIdx.x, tid = threadIdx.x;
  if (blk < 512) {                       // ---- h convert ----
    int i = (blk * 256 + tid) * 8;
    float4 a = *(const float4*)(h + i);
    float4 b = *(const float4*)(h + i + 4);
    h8 o = { (_Float16)a.x, (_Float16)a.y, (_Float16)a.z, (_Float16)a.w,
             (_Float16)b.x, (_Float16)b.y, (_Float16)b.z, (_Float16)b.w };
    *(h8*)(hF + i) = o;
  } else if (blk < 704) {                // ---- W pack ----
    int j = (blk - 512) * 256 + tid;     // [0, 49152)
    int hh = j / (48 * DD);
    int r  = j % (48 * DD);
    int n  = r / DD;
    int d  = r % DD;
    float val;
    if (n < 16)      val = WQ[((size_t)hh * DD + d) * 16 + n] * QSCALE;
    else if (n < 32) val = WK[((size_t)hh * DD + d) * 16 + (n - 16)];
    else             val = WV[((size_t)hh * DD + d) * 16 + (n - 32)];
    Wc[j] = (_Float16)val;
  } else {                               // ---- mask byte map ----
    int t = (blk - 704) * 256 + tid;     // [0, 524288)
    const int* m = mask + (size_t)t * 8;
    int4 m0 = *(const int4*)m;
    int4 m1 = *(const int4*)(m + 4);
    u32 byte = (m0.x > 0) | ((m0.y > 0) << 1) | ((m0.z > 0) << 2) | ((m0.w > 0) << 3)
             | ((m1.x > 0) << 4) | ((m1.y > 0) << 5) | ((m1.z > 0) << 6) | ((m1.w > 0) << 7);
    mb[t] = (u8)byte;
  }
}

// ---------------------------------------------------------------------------
// Kernel 2: MFMA projection (f16). One wave per (bh, 64-row g-tile):
// [64x128] x [128x48] via 4 m-tiles x 3 n-tiles x 4 k-steps of 16x16x32_f16.
// ---------------------------------------------------------------------------
__global__ __launch_bounds__(64) void proj_mfma(
    const _Float16* __restrict__ hF, const _Float16* __restrict__ Wc,
    _Float16* __restrict__ Qh, _Float16* __restrict__ Kh, _Float16* __restrict__ Vt)
{
  const int bh = blockIdx.x >> 5;
  const int gt = blockIdx.x & 31;
  const int b  = bh >> 3;
  const int hh = bh & (HH - 1);
  const int lane = threadIdx.x;
  const int col  = lane & 15;
  const int quad = lane >> 4;
  const int g0 = gt * 64;

  const _Float16* hb = hF + (size_t)b * GG * DD;
  const _Float16* W  = Wc + (size_t)hh * 48 * DD;

  f32x4 acc[4][3];
  #pragma unroll
  for (int mt = 0; mt < 4; ++mt)
    #pragma unroll
    for (int nt = 0; nt < 3; ++nt)
      acc[mt][nt] = (f32x4){0.f, 0.f, 0.f, 0.f};

  #pragma unroll
  for (int s = 0; s < 4; ++s) {
    h8 a[4], bw[3];
    #pragma unroll
    for (int mt = 0; mt < 4; ++mt)
      a[mt] = *(const h8*)(hb + (size_t)(g0 + mt * 16 + col) * DD + s * 32 + quad * 8);
    #pragma unroll
    for (int nt = 0; nt < 3; ++nt)
      bw[nt] = *(const h8*)(W + (size_t)(nt * 16 + col) * DD + s * 32 + quad * 8);
    #pragma unroll
    for (int mt = 0; mt < 4; ++mt)
      #pragma unroll
      for (int nt = 0; nt < 3; ++nt)
        acc[mt][nt] = __builtin_amdgcn_mfma_f32_16x16x32_f16(a[mt], bw[nt], acc[mt][nt], 0, 0, 0);
  }

  #pragma unroll
  for (int mt = 0; mt < 4; ++mt) {
    #pragma unroll
    for (int r = 0; r < 4; ++r) {
      int g = g0 + mt * 16 + quad * 4 + r;
      Qh[((size_t)bh * GG + g) * 16 + col] = (_Float16)acc[mt][0][r];
      Kh[((size_t)bh * GG + g) * 16 + col] = (_Float16)acc[mt][1][r];
      Vt[((size_t)bh * 16 + col) * GG + g] = (_Float16)acc[mt][2][r];
    }
  }
}

// ---------------------------------------------------------------------------
// Kernel 3: flash attention, zero LDS. 16 q-rows/wave, 4096 waves.
// Per 16-key tile: S^T = K·Q^T via 16x16x16 (K-dim=16 exact); exp in-place;
// packed P is register-identical to the PV MFMA's B-operand; O^T = V^T·P.
// C-operand of S-MFMA seeded with -4.0: uniform exp2 shift (cancels in
// softmax) keeping f16 P well below overflow. Per-lane denominator (q=col),
// one 2-step butterfly at the end. float4 output stores.
// ---------------------------------------------------------------------------
__global__ __launch_bounds__(256) void attn_kernel(
    const _Float16* __restrict__ Qh, const _Float16* __restrict__ Kh,
    const _Float16* __restrict__ Vt, const u8* __restrict__ mb,
    float* __restrict__ out)
{
  const int tid = threadIdx.x, wave = tid >> 6, lane = tid & 63;
  const int col = lane & 15, quad = lane >> 4;
  const int bh = blockIdx.x >> 5;
  const int qb = (blockIdx.x & 31) * 64 + wave * 16;

  // Q B-frag (16x16x16): B[k=dim][n=q]: n=col, k=quad*4+j  -> 8B load
  const h4 qf = *(const h4*)(Qh + ((size_t)bh * GG + qb + col) * 16 + quad * 4);

  const _Float16* Kb = Kh + (size_t)bh * GG * 16;
  const _Float16* Vb = Vt + ((size_t)bh * 16 + col) * GG;   // row col = vdim
  const u8* mrow = mb + (size_t)(qb + col) * (GG / 8);

  f32x4 acc = {0.f, 0.f, 0.f, 0.f};
  const f32x4 cinit = {-4.f, -4.f, -4.f, -4.f};
  float lsum = 0.f;

  for (int g8 = 0; g8 < GG / 128; ++g8) {     // 16 groups of 8 key-tiles
    uint4 mv = *(const uint4*)(mrow + g8 * 16);   // this q-row's next 128 mask bits
    u64 w0 = (u64)mv.x | ((u64)mv.y << 32);
    u64 w1 = (u64)mv.z | ((u64)mv.w << 32);
    #pragma unroll
    for (int k8 = 0; k8 < 8; ++k8) {
      const int kb = g8 * 128 + k8 * 16;
      // K A-frag: A[m=key][k=dim]: m=col -> key kb+col, dims quad*4..+3 (8B)
      h4 kf = *(const h4*)(Kb + (size_t)(kb + col) * 16 + quad * 4);
      // V A-frag: A[m=vdim][k=key]: m=col=vdim, keys kb+quad*4..+3 (8B)
      h4 vf = *(const h4*)(Vb + kb + quad * 4);

      // S^T[key=quad*4+r][q=col], pre-shifted by -4
      f32x4 s = MFMA16(kf, qf, cinit);

      u64 w = (k8 < 4) ? w0 : w1;
      u32 bits = (u32)(w >> ((k8 & 3) * 16 + quad * 4)) & 0xFu;
      float p0 = (bits & 1u) ? 0.f : EXP2F(s[0]);
      float p1 = (bits & 2u) ? 0.f : EXP2F(s[1]);
      float p2 = (bits & 4u) ? 0.f : EXP2F(s[2]);
      float p3 = (bits & 8u) ? 0.f : EXP2F(s[3]);
      lsum += (p0 + p1) + (p2 + p3);

      // P pack: exactly the PV B-operand (k=key=quad*4+j, n=q=col)
      h2 a01 = __builtin_bit_cast(h2, __builtin_amdgcn_cvt_pkrtz(p0, p1));
      h2 a23 = __builtin_bit_cast(h2, __builtin_amdgcn_cvt_pkrtz(p2, p3));
      h4 pf = __builtin_shufflevector(a01, a23, 0, 1, 2, 3);

      // O^T[vdim][q] += V^T · P
      acc = MFMA16(vf, pf, acc);
    }
  }

  // denominator for q=col: reduce over the 4 quads
  float l = lsum;
  l += __shfl_xor(l, 16, 64);
  l += __shfl_xor(l, 32, 64);
  float rl = (l > 0.f) ? (1.f / l) : 0.f;     // all-masked row -> 0 (matches ref)

  // O^T C-layout: lane holds vdims quad*4+r of q=col -> one float4 store
  float4 o = { acc[0] * rl, acc[1] * rl, acc[2] * rl, acc[3] * rl };
  *(float4*)(out + ((size_t)bh * GG + qb + col) * 16 + quad * 4) = o;
}

// ---------------------------------------------------------------------------
extern "C" void kernel_launch(void* const* d_in, const int* in_sizes, int n_in,
                              void* d_out, int out_size, void* d_ws, size_t ws_size,
                              hipStream_t stream) {
  const float* h    = (const float*)d_in[0];
  const int*   mask = (const int*)d_in[1];
  const float* WQ   = (const float*)d_in[2];
  const float* WK   = (const float*)d_in[3];
  const float* WV   = (const float*)d_in[4];
  float* out = (float*)d_out;
  char* ws = (char*)d_ws;     // uses ~8.6 MB
  _Float16* Qh = (_Float16*)(ws + OFF_Q);
  _Float16* Kh = (_Float16*)(ws + OFF_K);
  _Float16* Vt = (_Float16*)(ws + OFF_V);
  u8*       mb = (u8*)(ws + OFF_M);
  _Float16* hF = (_Float16*)(ws + OFF_H);
  _Float16* Wc = (_Float16*)(ws + OFF_W);

  hipLaunchKernelGGL(prep_kernel, dim3(2752), dim3(256), 0, stream,
                     h, mask, WQ, WK, WV, hF, Wc, mb);
  hipLaunchKernelGGL(proj_mfma, dim3(BH * (GG / 64)), dim3(64), 0, stream,
                     hF, Wc, Qh, Kh, Vt);
  hipLaunchKernelGGL(attn_kernel, dim3(BH * (GG / 64)), dim3(256), 0, stream,
                     Qh, Kh, Vt, mb, out);
}